// Round 1
// 569.707 us; speedup vs baseline: 1.0462x; 1.0462x over previous
//
#include <hip/hip_runtime.h>

typedef _Float16 half8 __attribute__((ext_vector_type(8)));
typedef __fp16   pk2   __attribute__((ext_vector_type(2)));
typedef float    f32x4 __attribute__((ext_vector_type(4)));

#define GLOBAL_AS __attribute__((address_space(1)))
#define LDS_AS    __attribute__((address_space(3)))

static constexpr int Bb = 32;
static constexpr int Nn = 2048;
static constexpr int Dd = 1024;
static constexpr int M  = Bb * Nn;   // 65536 rows of the big GEMM

// ---------------------------------------------------------------------------
// Packed operand layout (shared by prep kernels and gemm8):
// chunk = one (tile, half) = 128 rows/cols x 64 k of f16 = 16 KB, staged
// linearly by global_load_lds. Within a chunk, half8 unit u = q*128 + s
// (q = k-octet 0..7) holds logical row  r = s ^ (2*(q&3))  -- the XOR is the
// LDS bank swizzle, pre-baked into the GLOBAL layout (linear LDS dest +
// inverse-swizzled source + swizzled ds_read, per the both-sides rule).
// A_p chunks: [mtile(256)][t(16)][h(2)]   W1TT chunks: [et(4)][t(16)][h(2)]
// ---------------------------------------------------------------------------

// Kernel 1a: pack W1 (f32 [d][e]) -> swizzled f16 chunks.
__global__ void prep_w1(const float* __restrict__ W1, _Float16* __restrict__ W1TT) {
    int g = blockIdx.x * 256 + threadIdx.x;   // 131072 half8 units
    int chunk = g >> 10;                      // et*32 + t*2 + h
    int u = g & 1023;
    int q = u >> 7, sc = u & 127;
    int cl = sc ^ (2 * (q & 3));
    int et = chunk >> 5, t = (chunk >> 1) & 15, h = chunk & 1;
    int e  = et * 256 + h * 128 + cl;
    int k0 = t * 64 + q * 8;
    half8 hh;
#pragma unroll
    for (int j = 0; j < 8; ++j)
        hh[j] = (_Float16)W1[(size_t)(k0 + j) * Dd + e];
    *(half8*)(W1TT + (size_t)g * 8) = hh;
}

// Kernel 1b: convert+pack encoded (f32 [m][d]) -> swizzled f16 chunks.
// LDS-staged transpose keeps both the 256 MiB read and 128 MiB write coalesced.
__global__ void prep_enc(const float* __restrict__ A, _Float16* __restrict__ A_p) {
    __shared__ _Float16 T[128 * 64];          // 16 KB, slot-XOR banked
    const int c = blockIdx.x;                 // 8192 chunks
    const int tid = threadIdx.x;
    const int mtile = c >> 5, t = (c >> 1) & 15, h = c & 1;
    const int r = tid >> 1, kh = tid & 1;     // thread reads 128B of one row
    const float* src = A + (size_t)(mtile * 256 + h * 128 + r) * Dd + t * 64 + kh * 32;
    const int rx = r & 7;
#pragma unroll
    for (int i = 0; i < 4; ++i) {
        f32x4 a  = *(const f32x4*)(src + i * 8);
        f32x4 b2 = *(const f32x4*)(src + i * 8 + 4);
        half8 hh; pk2 p;
        p = __builtin_amdgcn_cvt_pkrtz(a.x, a.y);   hh[0] = p[0]; hh[1] = p[1];
        p = __builtin_amdgcn_cvt_pkrtz(a.z, a.w);   hh[2] = p[0]; hh[3] = p[1];
        p = __builtin_amdgcn_cvt_pkrtz(b2.x, b2.y); hh[4] = p[0]; hh[5] = p[1];
        p = __builtin_amdgcn_cvt_pkrtz(b2.z, b2.w); hh[6] = p[0]; hh[7] = p[1];
        *(half8*)(T + r * 64 + (((kh * 4 + i) ^ rx) * 8)) = hh;   // slot ^= r&7
    }
    __syncthreads();
    const size_t cb = (size_t)c * 8192;
#pragma unroll
    for (int i = 0; i < 4; ++i) {
        int u = i * 256 + tid;
        int q = u >> 7, sr = u & 127;
        int lr = sr ^ (2 * (q & 3));
        half8 hh = *(const half8*)(T + lr * 64 + ((q ^ (lr & 7)) * 8));
        *(half8*)(A_p + cb + (size_t)u * 8) = hh;  // fully coalesced 16B stores
    }
}

// ---------------------------------------------------------------------------
// Kernel 2: dec[b][e] = decoder_state[b] @ W2   (32x1024)
// ---------------------------------------------------------------------------
__global__ void dec_kernel(const float* __restrict__ ds, const float* __restrict__ W2,
                           float* __restrict__ dec) {
    __shared__ float part[4][64];
    int b = blockIdx.x, ech = blockIdx.y;
    int tid = threadIdx.x;
    int e = ech * 64 + (tid & 63);
    int dc = tid >> 6;
    float acc = 0.f;
#pragma unroll 4
    for (int d = dc * 256; d < dc * 256 + 256; ++d)
        acc += ds[b * Dd + d] * W2[(size_t)d * Dd + e];
    part[dc][tid & 63] = acc;
    __syncthreads();
    if (tid < 64)
        dec[b * Dd + e] = part[0][tid] + part[1][tid] + part[2][tid] + part[3][tid];
}

// ---------------------------------------------------------------------------
// Kernel 3: 256x256-tile, 8-wave, 4-phase-per-K-tile GEMM with counted vmcnt.
// 16 K-tiles of BK=64; LDS = 2 dbuf x (A 32K + B 32K) = 128 KB (dynamic).
// Waves: wr = wid>>2 (2), wc = wid&3 (4); wave output 128x64, rows/cols
// striped at 16 so phase quadrants map to A/B halves.
// Phase p of tile t:  ph1{read A0+B0 | stage (t+1).A1 | vmcnt(10)}
//                     ph2{read B1    | stage (t+2).A0 | vmcnt(10)}
//                     ph3{read A1    | stage (t+2).B0 | no wait  }
//                     ph4{           | stage (t+2).B1 | vmcnt(10)}
// each phase: ... s_barrier; lgkmcnt(0); setprio(1); 16 MFMA; setprio(0); s_barrier
// Tail waits derived exactly: t=14 ph2->8 ph4->4 ; t=15 ph1->2 ph2->0.
// ---------------------------------------------------------------------------
__global__ __launch_bounds__(512) void gemm8(
    const _Float16* __restrict__ A_p, const _Float16* __restrict__ W1TT,
    const float* __restrict__ dec, const float* __restrict__ vt,
    float* __restrict__ u_part)          // [4][65536]
{
    extern __shared__ _Float16 lds[];    // 65536 halfs = 128 KB

    const int g  = blockIdx.x;                   // 0..1023
    const int wg = (g & 7) * 128 + (g >> 3);     // XCD-chunked swizzle (1024%8==0)
    const int et    = wg & 3;                    // 4 consecutive wg share mtile
    const int mtile = wg >> 2;

    const int tid  = threadIdx.x;
    const int lane = tid & 63, wid = tid >> 6;
    const int wr = wid >> 2, wc = wid & 3;
    const int qq = lane >> 4, l15 = lane & 15;
    const int l15s = l15 ^ (2 * qq);             // read-side bank swizzle
    const int rA = wr * 16 + l15s;
    const int rB = wc * 16 + l15s;

    f32x4 acc[8][4] = {};

    // ---- epilogue operands BEFORE the pipeline (keeps vmcnt clean) ----
    const int b = mtile >> 3;                    // 8 mtiles per batch row
    float vtv[4], dcv[4];
#pragma unroll
    for (int nf = 0; nf < 4; ++nf) {
        int e = et * 256 + (nf >> 1) * 128 + (nf & 1) * 64 + wc * 16 + l15;
        vtv[nf] = vt[e];
        dcv[nf] = dec[b * Dd + e];
    }
    asm volatile("s_waitcnt vmcnt(0)" ::: "memory");

    const size_t abase = (size_t)mtile * 32 * 8192;
    const size_t bbase = (size_t)et * 32 * 8192;
    const int uoff = tid * 8;                    // per-thread 16B within chunk

    auto stA = [&](int t2, int h) {
        const _Float16* gp = A_p + abase + ((size_t)(t2 * 2 + h) << 13) + uoff;
        _Float16* lp = lds + ((((t2 & 1) * 2 + h) << 13) + (wid << 9));
        __builtin_amdgcn_global_load_lds((const GLOBAL_AS void*)gp,
                                         (LDS_AS void*)lp, 16, 0, 0);
        __builtin_amdgcn_global_load_lds((const GLOBAL_AS void*)(gp + 4096),
                                         (LDS_AS void*)(lp + 4096), 16, 0, 0);
    };
    auto stB = [&](int t2, int h) {
        const _Float16* gp = W1TT + bbase + ((size_t)(t2 * 2 + h) << 13) + uoff;
        _Float16* lp = lds + (32768 + (((t2 & 1) * 2 + h) << 13) + (wid << 9));
        __builtin_amdgcn_global_load_lds((const GLOBAL_AS void*)gp,
                                         (LDS_AS void*)lp, 16, 0, 0);
        __builtin_amdgcn_global_load_lds((const GLOBAL_AS void*)(gp + 4096),
                                         (LDS_AS void*)(lp + 4096), 16, 0, 0);
    };

    // prologue: virtual tiles (-2),(-1) of the steady cadence (14 loads)
    stA(0, 0); stB(0, 0); stB(0, 1); stA(0, 1); stA(1, 0); stB(1, 0); stB(1, 1);
    asm volatile("s_waitcnt vmcnt(10)" ::: "memory");
    asm volatile("s_barrier" ::: "memory");

    half8 af[4][2], bf0[2][2], bf1[2][2];

#pragma unroll 1
    for (int t = 0; t < 16; ++t) {
        const int Ab0 = (t & 1) * 16384;          // A slot, half0 (halfword units)
        const int Ab1 = Ab0 + 8192;
        const int Bb0 = 32768 + Ab0;              // B slot, half0
        const int Bb1 = Bb0 + 8192;

        // ---------------- phase 1: A0 + B0, MFMA mf0-3 x nf0-1 ----------------
#pragma unroll
        for (int ks = 0; ks < 2; ++ks) {
            const int qb = ((ks * 4 + qq) * 128) * 8;
#pragma unroll
            for (int m = 0; m < 4; ++m)
                af[m][ks] = *(const half8*)&lds[Ab0 + qb + (m * 32 + rA) * 8];
#pragma unroll
            for (int j = 0; j < 2; ++j)
                bf0[j][ks] = *(const half8*)&lds[Bb0 + qb + (j * 64 + rB) * 8];
        }
        if (t < 15) stA(t + 1, 1);
        if (t < 15) asm volatile("s_waitcnt vmcnt(10)" ::: "memory");
        else        asm volatile("s_waitcnt vmcnt(2)"  ::: "memory");
        asm volatile("s_barrier" ::: "memory");
        asm volatile("s_waitcnt lgkmcnt(0)" ::: "memory");
        __builtin_amdgcn_s_setprio(1);
#pragma unroll
        for (int m = 0; m < 4; ++m)
#pragma unroll
            for (int j = 0; j < 2; ++j) {
                acc[m][j] = __builtin_amdgcn_mfma_f32_16x16x32_f16(af[m][0], bf0[j][0], acc[m][j], 0, 0, 0);
                acc[m][j] = __builtin_amdgcn_mfma_f32_16x16x32_f16(af[m][1], bf0[j][1], acc[m][j], 0, 0, 0);
            }
        __builtin_amdgcn_s_setprio(0);
        asm volatile("s_barrier" ::: "memory");

        // ---------------- phase 2: B1, MFMA mf0-3 x nf2-3 ---------------------
#pragma unroll
        for (int ks = 0; ks < 2; ++ks) {
            const int qb = ((ks * 4 + qq) * 128) * 8;
#pragma unroll
            for (int j = 0; j < 2; ++j)
                bf1[j][ks] = *(const half8*)&lds[Bb1 + qb + (j * 64 + rB) * 8];
        }
        if (t < 14) stA(t + 2, 0);
        if (t < 14)       asm volatile("s_waitcnt vmcnt(10)" ::: "memory");
        else if (t == 14) asm volatile("s_waitcnt vmcnt(8)"  ::: "memory");
        else              asm volatile("s_waitcnt vmcnt(0)"  ::: "memory");
        asm volatile("s_barrier" ::: "memory");
        asm volatile("s_waitcnt lgkmcnt(0)" ::: "memory");
        __builtin_amdgcn_s_setprio(1);
#pragma unroll
        for (int m = 0; m < 4; ++m)
#pragma unroll
            for (int j = 0; j < 2; ++j) {
                acc[m][2 + j] = __builtin_amdgcn_mfma_f32_16x16x32_f16(af[m][0], bf1[j][0], acc[m][2 + j], 0, 0, 0);
                acc[m][2 + j] = __builtin_amdgcn_mfma_f32_16x16x32_f16(af[m][1], bf1[j][1], acc[m][2 + j], 0, 0, 0);
            }
        __builtin_amdgcn_s_setprio(0);
        asm volatile("s_barrier" ::: "memory");

        // ---------------- phase 3: A1, MFMA mf4-7 x nf0-1 (bf0 in regs) -------
#pragma unroll
        for (int ks = 0; ks < 2; ++ks) {
            const int qb = ((ks * 4 + qq) * 128) * 8;
#pragma unroll
            for (int m = 0; m < 4; ++m)
                af[m][ks] = *(const half8*)&lds[Ab1 + qb + (m * 32 + rA) * 8];
        }
        if (t < 14) stB(t + 2, 0);
        asm volatile("s_barrier" ::: "memory");
        asm volatile("s_waitcnt lgkmcnt(0)" ::: "memory");
        __builtin_amdgcn_s_setprio(1);
#pragma unroll
        for (int m = 0; m < 4; ++m)
#pragma unroll
            for (int j = 0; j < 2; ++j) {
                acc[4 + m][j] = __builtin_amdgcn_mfma_f32_16x16x32_f16(af[m][0], bf0[j][0], acc[4 + m][j], 0, 0, 0);
                acc[4 + m][j] = __builtin_amdgcn_mfma_f32_16x16x32_f16(af[m][1], bf0[j][1], acc[4 + m][j], 0, 0, 0);
            }
        __builtin_amdgcn_s_setprio(0);
        asm volatile("s_barrier" ::: "memory");

        // ---------------- phase 4: MFMA mf4-7 x nf2-3 (all regs) --------------
        if (t < 14) stB(t + 2, 1);
        if (t < 14)       asm volatile("s_waitcnt vmcnt(10)" ::: "memory");
        else if (t == 14) asm volatile("s_waitcnt vmcnt(4)"  ::: "memory");
        // t == 15: nothing outstanding
        asm volatile("s_barrier" ::: "memory");
        __builtin_amdgcn_s_setprio(1);
#pragma unroll
        for (int m = 0; m < 4; ++m)
#pragma unroll
            for (int j = 0; j < 2; ++j) {
                acc[4 + m][2 + j] = __builtin_amdgcn_mfma_f32_16x16x32_f16(af[m][0], bf1[j][0], acc[4 + m][2 + j], 0, 0, 0);
                acc[4 + m][2 + j] = __builtin_amdgcn_mfma_f32_16x16x32_f16(af[m][1], bf1[j][1], acc[4 + m][2 + j], 0, 0, 0);
            }
        __builtin_amdgcn_s_setprio(0);
        asm volatile("s_barrier" ::: "memory");
    }

    // ---- epilogue: tanh(c + dec) * vt, reduce over this block's 256 cols ----
    float* usum = (float*)lds;   // [4 wc][256 rows]; all staging drained by t=15
#pragma unroll
    for (int hm = 0; hm < 8; ++hm) {
        const int h = hm >> 2, m = hm & 3;
#pragma unroll
        for (int r = 0; r < 4; ++r) {
            float s = 0.f;
#pragma unroll
            for (int nf = 0; nf < 4; ++nf) {
                float x  = acc[hm][nf][r] + dcv[nf];
                float ex = __expf(2.f * x);
                s += (1.f - 2.f * __builtin_amdgcn_rcpf(ex + 1.f)) * vtv[nf];
            }
#pragma unroll
            for (int off = 1; off < 16; off <<= 1) s += __shfl_xor(s, off, 16);
            if (l15 == 0)
                usum[wc * 256 + h * 128 + m * 32 + wr * 16 + qq * 4 + r] = s;
        }
    }
    __syncthreads();
    if (tid < 256) {
        float v = usum[tid] + usum[256 + tid] + usum[512 + tid] + usum[768 + tid];
        u_part[(size_t)et * M + (size_t)mtile * 256 + tid] = v;
    }
}

// ---------------------------------------------------------------------------
// Kernel 4: masked log-softmax over N=2048 per batch row (4 partial slices).
// ---------------------------------------------------------------------------
__global__ void softmax_k(const float* __restrict__ up, const int* __restrict__ mask,
                          float* __restrict__ out) {
    __shared__ float red[8];
    int b = blockIdx.x, tid = threadIdx.x;
    float l[8];
#pragma unroll
    for (int i = 0; i < 8; ++i) {
        int n = i * 256 + tid;
        float s = up[(size_t)b * Nn + n];
#pragma unroll
        for (int et = 1; et < 4; ++et) s += up[(size_t)et * M + (size_t)b * Nn + n];
        l[i] = s + (mask[b * Nn + n] ? 0.f : -103.278931f);  // ln(2^-149)
    }
    float m = l[0];
#pragma unroll
    for (int i = 1; i < 8; ++i) m = fmaxf(m, l[i]);
#pragma unroll
    for (int o = 32; o >= 1; o >>= 1) m = fmaxf(m, __shfl_xor(m, o, 64));
    if ((tid & 63) == 0) red[tid >> 6] = m;
    __syncthreads();
    m = fmaxf(fmaxf(red[0], red[1]), fmaxf(red[2], red[3]));
    float s = 0.f;
#pragma unroll
    for (int i = 0; i < 8; ++i) s += expf(l[i] - m);
#pragma unroll
    for (int o = 32; o >= 1; o >>= 1) s += __shfl_xor(s, o, 64);
    if ((tid & 63) == 0) red[4 + (tid >> 6)] = s;
    __syncthreads();
    float lse = m + logf(red[4] + red[5] + red[6] + red[7]);
#pragma unroll
    for (int i = 0; i < 8; ++i)
        out[(size_t)b * Nn + i * 256 + tid] = l[i] - lse;
}

// ---------------------------------------------------------------------------
extern "C" void kernel_launch(void* const* d_in, const int* in_sizes, int n_in,
                              void* d_out, int out_size, void* d_ws, size_t ws_size,
                              hipStream_t stream) {
    const float* encoded = (const float*)d_in[0];
    const float* dstate  = (const float*)d_in[1];
    const int*   mask    = (const int*)d_in[2];
    const float* W1      = (const float*)d_in[3];
    const float* W2      = (const float*)d_in[4];
    const float* vt      = (const float*)d_in[5];
    float* out = (float*)d_out;

    // ws layout: u_part (1 MiB) | dec (128 KB) | W1TT (2 MiB) | A_p (128 MiB)
    char* ws = (char*)d_ws;
    float*    u_part = (float*)ws;
    float*    dec    = (float*)(ws + (size_t)4 * M * 4);
    _Float16* W1TT   = (_Float16*)(ws + (size_t)4 * M * 4 + (size_t)Bb * Dd * 4);
    _Float16* A_p    = (_Float16*)(ws + (size_t)4 * M * 4 + (size_t)Bb * Dd * 4
                                   + (size_t)Dd * Dd * 2);

    static bool attr_done = false;
    if (!attr_done) {
        hipFuncSetAttribute(reinterpret_cast<const void*>(gemm8),
                            hipFuncAttributeMaxDynamicSharedMemorySize, 131072);
        attr_done = true;
    }

    prep_w1<<<512, 256, 0, stream>>>(W1, W1TT);
    dec_kernel<<<dim3(32, 16), 256, 0, stream>>>(dstate, W2, dec);
    prep_enc<<<8192, 256, 0, stream>>>(encoded, A_p);
    gemm8<<<1024, 512, 131072, stream>>>(A_p, W1TT, dec, vt, u_part);
    softmax_k<<<32, 256, 0, stream>>>(u_part, mask, out);
}